// Round 2
// baseline (9463.856 us; speedup 1.0000x reference)
//
#include <hip/hip_runtime.h>

static constexpr int N_NODES = 100000;
static constexpr int N_GAMES = 1600000;

// ---------------------------------------------------------------------------
// degree count: every entry of w2b (both rows) is a dst exactly once
__global__ void count_deg_kernel(const int* __restrict__ idx, int* __restrict__ cnt, int n) {
    int i = blockIdx.x * blockDim.x + threadIdx.x;
    if (i < n) atomicAdd(&cnt[idx[i]], 1);
}

__global__ void dinv_kernel(const int* __restrict__ cnt, float* __restrict__ dinv, int n) {
    int i = blockIdx.x * blockDim.x + threadIdx.x;
    if (i < n) dinv[i] = rsqrtf((float)cnt[i] + 1.0f);
}

// ---------------------------------------------------------------------------
// xw = h @ W   (no bias here; bias is added once in combine, matching ref)
template<int FIN, int FOUT>
__global__ void node_linear_kernel(const float* __restrict__ h, const float* __restrict__ W,
                                   float* __restrict__ xw, int n) {
    __shared__ float sW[FIN * FOUT];
    for (int k = threadIdx.x; k < FIN * FOUT; k += blockDim.x) sW[k] = W[k];
    __syncthreads();
    int i = blockIdx.x * blockDim.x + threadIdx.x;
    if (i >= n) return;
    float hin[FIN];
#pragma unroll
    for (int k = 0; k < FIN; ++k) hin[k] = h[(size_t)i * FIN + k];
#pragma unroll
    for (int j = 0; j < FOUT; ++j) {
        float acc = 0.0f;
#pragma unroll
        for (int k = 0; k < FIN; ++k) acc += hin[k] * sW[k * FOUT + j];
        xw[(size_t)i * FOUT + j] = acc;
    }
}

// ---------------------------------------------------------------------------
// one thread per GAME; handles both edge directions (norm is symmetric)
template<int FOUT>
__global__ void edge_scatter_kernel(const int* __restrict__ wa, const int* __restrict__ wb,
                                    const float* __restrict__ dinv, const float* __restrict__ xw,
                                    float* __restrict__ msg, int ngames) {
    int e = blockIdx.x * blockDim.x + threadIdx.x;
    if (e >= ngames) return;
    int a = wa[e], b = wb[e];
    float norm = dinv[a] * dinv[b];
    const float4* xw4 = reinterpret_cast<const float4*>(xw);
#pragma unroll
    for (int f4 = 0; f4 < FOUT / 4; ++f4) {
        float4 xa = xw4[(size_t)a * (FOUT / 4) + f4];
        float4 xb = xw4[(size_t)b * (FOUT / 4) + f4];
        float* mb = msg + (size_t)b * FOUT + f4 * 4;
        float* ma = msg + (size_t)a * FOUT + f4 * 4;
        atomicAdd(mb + 0, xa.x * norm);
        atomicAdd(mb + 1, xa.y * norm);
        atomicAdd(mb + 2, xa.z * norm);
        atomicAdd(mb + 3, xa.w * norm);
        atomicAdd(ma + 0, xb.x * norm);
        atomicAdd(ma + 1, xb.y * norm);
        atomicAdd(ma + 2, xb.z * norm);
        atomicAdd(ma + 3, xb.w * norm);
    }
}

// ---------------------------------------------------------------------------
// out = relu(msg + xw * dinv^2 + b)
template<int FOUT>
__global__ void combine_relu_kernel(const float* __restrict__ msg, const float* __restrict__ xw,
                                    const float* __restrict__ dinv, const float* __restrict__ bias,
                                    float* __restrict__ out, int n) {
    int idx = blockIdx.x * blockDim.x + threadIdx.x;
    if (idx >= n * FOUT) return;
    int i = idx / FOUT;
    int f = idx - i * FOUT;
    float d = dinv[i];
    float v = msg[idx] + xw[idx] * d * d + bias[f];
    out[idx] = fmaxf(v, 0.0f);
}

// ---------------------------------------------------------------------------
// per-game MLP: concat(h[a], h[b]) @ lw1 + lb1 -> @ lw2 + lb2  (no relu)
__global__ void edge_mlp_kernel(const int* __restrict__ wa, const int* __restrict__ wb,
                                const float* __restrict__ h,
                                const float* __restrict__ lw1, const float* __restrict__ lb1,
                                const float* __restrict__ lw2, const float* __restrict__ lb2,
                                float* __restrict__ out, int ngames) {
    __shared__ float sW1[256];
    __shared__ float sB1[4];
    __shared__ float sW2[12];
    __shared__ float sB2[3];
    for (int k = threadIdx.x; k < 256; k += blockDim.x) sW1[k] = lw1[k];
    if (threadIdx.x < 4) sB1[threadIdx.x] = lb1[threadIdx.x];
    if (threadIdx.x < 12) sW2[threadIdx.x] = lw2[threadIdx.x];
    if (threadIdx.x < 3) sB2[threadIdx.x] = lb2[threadIdx.x];
    __syncthreads();
    int e = blockIdx.x * blockDim.x + threadIdx.x;
    if (e >= ngames) return;
    int a = wa[e], b = wb[e];
    float hid0 = sB1[0], hid1 = sB1[1], hid2 = sB1[2], hid3 = sB1[3];
    const float4* h4 = reinterpret_cast<const float4*>(h);
#pragma unroll
    for (int k4 = 0; k4 < 8; ++k4) {
        float4 v = h4[(size_t)a * 8 + k4];
        const float* w = sW1 + (k4 * 4) * 4;  // rows k4*4 .. k4*4+3 of lw1[64][4]
        hid0 += v.x * w[0] + v.y * w[4] + v.z * w[8]  + v.w * w[12];
        hid1 += v.x * w[1] + v.y * w[5] + v.z * w[9]  + v.w * w[13];
        hid2 += v.x * w[2] + v.y * w[6] + v.z * w[10] + v.w * w[14];
        hid3 += v.x * w[3] + v.y * w[7] + v.z * w[11] + v.w * w[15];
    }
#pragma unroll
    for (int k4 = 0; k4 < 8; ++k4) {
        float4 v = h4[(size_t)b * 8 + k4];
        const float* w = sW1 + (32 + k4 * 4) * 4;  // rows 32+k4*4 .. of lw1
        hid0 += v.x * w[0] + v.y * w[4] + v.z * w[8]  + v.w * w[12];
        hid1 += v.x * w[1] + v.y * w[5] + v.z * w[9]  + v.w * w[13];
        hid2 += v.x * w[2] + v.y * w[6] + v.z * w[10] + v.w * w[14];
        hid3 += v.x * w[3] + v.y * w[7] + v.z * w[11] + v.w * w[15];
    }
    // lw2 is [4][3] row-major
    float p0 = sB2[0] + hid0 * sW2[0] + hid1 * sW2[3] + hid2 * sW2[6] + hid3 * sW2[9];
    float p1 = sB2[1] + hid0 * sW2[1] + hid1 * sW2[4] + hid2 * sW2[7] + hid3 * sW2[10];
    float p2 = sB2[2] + hid0 * sW2[2] + hid1 * sW2[5] + hid2 * sW2[8] + hid3 * sW2[11];
    out[(size_t)e * 3 + 0] = p0;
    out[(size_t)e * 3 + 1] = p1;
    out[(size_t)e * 3 + 2] = p2;
}

// ---------------------------------------------------------------------------
extern "C" void kernel_launch(void* const* d_in, const int* in_sizes, int n_in,
                              void* d_out, int out_size, void* d_ws, size_t ws_size,
                              hipStream_t stream) {
    (void)in_sizes; (void)n_in; (void)out_size; (void)ws_size;
    const float* x   = (const float*)d_in[0];
    // d_in[1] = edge_index (redundant: it is [w2b; w2b reversed]) — unused
    const int*   w2b = (const int*)d_in[2];
    const float* W1  = (const float*)d_in[3];
    const float* b1  = (const float*)d_in[4];
    const float* W2  = (const float*)d_in[5];
    const float* b2  = (const float*)d_in[6];
    const float* W3  = (const float*)d_in[7];
    const float* b3  = (const float*)d_in[8];
    const float* lw1 = (const float*)d_in[9];
    const float* lb1 = (const float*)d_in[10];
    const float* lw2 = (const float*)d_in[11];
    const float* lb2 = (const float*)d_in[12];
    float* out = (float*)d_out;

    char* ws = (char*)d_ws;
    size_t o = 0;
    auto alloc = [&](size_t bytes) -> void* {
        void* p = ws + o;
        o = (o + bytes + 255) & ~(size_t)255;
        return p;
    };
    int*   cnt  = (int*)  alloc((size_t)N_NODES * 4);
    float* dinv = (float*)alloc((size_t)N_NODES * 4);
    float* xw   = (float*)alloc((size_t)N_NODES * 32 * 4);
    float* msg  = (float*)alloc((size_t)N_NODES * 32 * 4);
    float* hbuf = (float*)alloc((size_t)N_NODES * 32 * 4);

    const int* wa = w2b;            // w2b[0][:]
    const int* wb = w2b + N_GAMES;  // w2b[1][:]

    const int BLK = 256;
    auto grid = [](long n, int blk) { return dim3((unsigned)((n + blk - 1) / blk)); };

    // degrees + dinv
    hipMemsetAsync(cnt, 0, (size_t)N_NODES * 4, stream);
    count_deg_kernel<<<grid(2L * N_GAMES, BLK), BLK, 0, stream>>>(w2b, cnt, 2 * N_GAMES);
    dinv_kernel<<<grid(N_NODES, BLK), BLK, 0, stream>>>(cnt, dinv, N_NODES);

    // ---- layer 1: 7 -> 8 ----
    node_linear_kernel<7, 8><<<grid(N_NODES, BLK), BLK, 0, stream>>>(x, W1, xw, N_NODES);
    hipMemsetAsync(msg, 0, (size_t)N_NODES * 8 * 4, stream);
    edge_scatter_kernel<8><<<grid(N_GAMES, BLK), BLK, 0, stream>>>(wa, wb, dinv, xw, msg, N_GAMES);
    combine_relu_kernel<8><<<grid((long)N_NODES * 8, BLK), BLK, 0, stream>>>(msg, xw, dinv, b1, hbuf, N_NODES);

    // ---- layer 2: 8 -> 16 ----
    node_linear_kernel<8, 16><<<grid(N_NODES, BLK), BLK, 0, stream>>>(hbuf, W2, xw, N_NODES);
    hipMemsetAsync(msg, 0, (size_t)N_NODES * 16 * 4, stream);
    edge_scatter_kernel<16><<<grid(N_GAMES, BLK), BLK, 0, stream>>>(wa, wb, dinv, xw, msg, N_GAMES);
    combine_relu_kernel<16><<<grid((long)N_NODES * 16, BLK), BLK, 0, stream>>>(msg, xw, dinv, b2, hbuf, N_NODES);

    // ---- layer 3: 16 -> 32 ----
    node_linear_kernel<16, 32><<<grid(N_NODES, BLK), BLK, 0, stream>>>(hbuf, W3, xw, N_NODES);
    hipMemsetAsync(msg, 0, (size_t)N_NODES * 32 * 4, stream);
    edge_scatter_kernel<32><<<grid(N_GAMES, BLK), BLK, 0, stream>>>(wa, wb, dinv, xw, msg, N_GAMES);
    combine_relu_kernel<32><<<grid((long)N_NODES * 32, BLK), BLK, 0, stream>>>(msg, xw, dinv, b3, hbuf, N_NODES);

    // ---- edge MLP ----
    edge_mlp_kernel<<<grid(N_GAMES, BLK), BLK, 0, stream>>>(wa, wb, hbuf, lw1, lb1, lw2, lb2, out, N_GAMES);
}

// Round 3
// 942.147 us; speedup vs baseline: 10.0450x; 10.0450x over previous
//
#include <hip/hip_runtime.h>

static constexpr int N_NODES = 100000;
static constexpr int N_GAMES = 1600000;
static constexpr int SCAN_T = 1024;

// ---------------------------------------------------------------------------
// degree count: every entry of w2b (both rows) is a dst exactly once
__global__ void count_deg_kernel(const int* __restrict__ idx, int* __restrict__ cnt, int n) {
    int i = blockIdx.x * blockDim.x + threadIdx.x;
    if (i < n) atomicAdd(&cnt[idx[i]], 1);
}

__global__ void dinv_kernel(const int* __restrict__ cnt, float* __restrict__ dinv, int n) {
    int i = blockIdx.x * blockDim.x + threadIdx.x;
    if (i < n) dinv[i] = rsqrtf((float)cnt[i] + 1.0f);
}

// ---------------------------------------------------------------------------
// single-block exclusive scan of cnt[0..N) -> off[0..N], off[N] = total
__global__ __launch_bounds__(SCAN_T) void scan_offsets_kernel(const int* __restrict__ cnt,
                                                              int* __restrict__ off) {
    __shared__ int part[SCAN_T];
    const int CH = (N_NODES + SCAN_T - 1) / SCAN_T;  // 98
    int t = threadIdx.x;
    int lo = t * CH;
    int hi = lo + CH; if (hi > N_NODES) hi = N_NODES;
    if (lo > N_NODES) lo = N_NODES;
    int s = 0;
    for (int i = lo; i < hi; ++i) s += cnt[i];
    part[t] = s;
    __syncthreads();
    // Hillis-Steele inclusive scan over 1024 partials
    for (int d = 1; d < SCAN_T; d <<= 1) {
        int v = (t >= d) ? part[t - d] : 0;
        __syncthreads();
        part[t] += v;
        __syncthreads();
    }
    int run = (t == 0) ? 0 : part[t - 1];
    for (int i = lo; i < hi; ++i) {
        off[i] = run;
        run += cnt[i];
    }
    if (t == 0) off[N_NODES] = part[SCAN_T - 1];
}

__global__ void copy_int_kernel(const int* __restrict__ src, int* __restrict__ dst, int n) {
    int i = blockIdx.x * blockDim.x + threadIdx.x;
    if (i < n) dst[i] = src[i];
}

// ---------------------------------------------------------------------------
// fill CSR: for each game (a,b): adj slot under dst=b gets a, and vice versa
__global__ void fill_csr_kernel(const int* __restrict__ wa, const int* __restrict__ wb,
                                int* __restrict__ cur, int* __restrict__ adj, int n) {
    int e = blockIdx.x * blockDim.x + threadIdx.x;
    if (e >= n) return;
    int a = wa[e], b = wb[e];
    int s1 = atomicAdd(&cur[b], 1);
    adj[s1] = a;
    int s2 = atomicAdd(&cur[a], 1);
    adj[s2] = b;
}

// ---------------------------------------------------------------------------
// xws = (h @ W) * dinv[i]   (bias deferred to gather; matches ref algebra)
template<int FIN, int FOUT>
__global__ void node_linear_scaled_kernel(const float* __restrict__ h, const float* __restrict__ W,
                                          const float* __restrict__ dinv,
                                          float* __restrict__ xws, int n) {
    __shared__ float sW[FIN * FOUT];
    for (int k = threadIdx.x; k < FIN * FOUT; k += blockDim.x) sW[k] = W[k];
    __syncthreads();
    int i = blockIdx.x * blockDim.x + threadIdx.x;
    if (i >= n) return;
    float hin[FIN];
#pragma unroll
    for (int k = 0; k < FIN; ++k) hin[k] = h[(size_t)i * FIN + k];
    float d = dinv[i];
#pragma unroll
    for (int j = 0; j < FOUT; ++j) {
        float acc = 0.0f;
#pragma unroll
        for (int k = 0; k < FIN; ++k) acc += hin[k] * sW[k * FOUT + j];
        xws[(size_t)i * FOUT + j] = acc * d;
    }
}

// ---------------------------------------------------------------------------
// out[i] = relu(dinv[i] * (sum_nbr xws[nbr] + xws[i]) + bias)
// thread = (node, feature-quad); quad fastest-varying for coalesced writes
template<int FOUT>
__global__ void gather_combine_kernel(const int* __restrict__ off, const int* __restrict__ adj,
                                      const float* __restrict__ dinv, const float* __restrict__ xws,
                                      const float* __restrict__ bias, float* __restrict__ out, int n) {
    constexpr int Q = FOUT / 4;
    int tid = blockIdx.x * blockDim.x + threadIdx.x;
    int i = tid / Q;
    int q = tid - i * Q;
    if (i >= n) return;
    const float4* x4 = reinterpret_cast<const float4*>(xws);
    float4 acc = x4[(size_t)i * Q + q];  // self-loop term
    int lo = off[i], hi = off[i + 1];
    for (int k = lo; k < hi; ++k) {
        int nb = adj[k];
        float4 v = x4[(size_t)nb * Q + q];
        acc.x += v.x; acc.y += v.y; acc.z += v.z; acc.w += v.w;
    }
    float d = dinv[i];
    float4 r;
    r.x = fmaxf(acc.x * d + bias[q * 4 + 0], 0.0f);
    r.y = fmaxf(acc.y * d + bias[q * 4 + 1], 0.0f);
    r.z = fmaxf(acc.z * d + bias[q * 4 + 2], 0.0f);
    r.w = fmaxf(acc.w * d + bias[q * 4 + 3], 0.0f);
    reinterpret_cast<float4*>(out)[(size_t)i * Q + q] = r;
}

// ---------------------------------------------------------------------------
// per-game MLP: concat(h[a], h[b]) @ lw1 + lb1 -> @ lw2 + lb2  (no relu)
__global__ void edge_mlp_kernel(const int* __restrict__ wa, const int* __restrict__ wb,
                                const float* __restrict__ h,
                                const float* __restrict__ lw1, const float* __restrict__ lb1,
                                const float* __restrict__ lw2, const float* __restrict__ lb2,
                                float* __restrict__ out, int ngames) {
    __shared__ float sW1[256];
    __shared__ float sB1[4];
    __shared__ float sW2[12];
    __shared__ float sB2[3];
    for (int k = threadIdx.x; k < 256; k += blockDim.x) sW1[k] = lw1[k];
    if (threadIdx.x < 4) sB1[threadIdx.x] = lb1[threadIdx.x];
    if (threadIdx.x < 12) sW2[threadIdx.x] = lw2[threadIdx.x];
    if (threadIdx.x < 3) sB2[threadIdx.x] = lb2[threadIdx.x];
    __syncthreads();
    int e = blockIdx.x * blockDim.x + threadIdx.x;
    if (e >= ngames) return;
    int a = wa[e], b = wb[e];
    float hid0 = sB1[0], hid1 = sB1[1], hid2 = sB1[2], hid3 = sB1[3];
    const float4* h4 = reinterpret_cast<const float4*>(h);
#pragma unroll
    for (int k4 = 0; k4 < 8; ++k4) {
        float4 v = h4[(size_t)a * 8 + k4];
        const float* w = sW1 + (k4 * 4) * 4;
        hid0 += v.x * w[0] + v.y * w[4] + v.z * w[8]  + v.w * w[12];
        hid1 += v.x * w[1] + v.y * w[5] + v.z * w[9]  + v.w * w[13];
        hid2 += v.x * w[2] + v.y * w[6] + v.z * w[10] + v.w * w[14];
        hid3 += v.x * w[3] + v.y * w[7] + v.z * w[11] + v.w * w[15];
    }
#pragma unroll
    for (int k4 = 0; k4 < 8; ++k4) {
        float4 v = h4[(size_t)b * 8 + k4];
        const float* w = sW1 + (32 + k4 * 4) * 4;
        hid0 += v.x * w[0] + v.y * w[4] + v.z * w[8]  + v.w * w[12];
        hid1 += v.x * w[1] + v.y * w[5] + v.z * w[9]  + v.w * w[13];
        hid2 += v.x * w[2] + v.y * w[6] + v.z * w[10] + v.w * w[14];
        hid3 += v.x * w[3] + v.y * w[7] + v.z * w[11] + v.w * w[15];
    }
    float p0 = sB2[0] + hid0 * sW2[0] + hid1 * sW2[3] + hid2 * sW2[6] + hid3 * sW2[9];
    float p1 = sB2[1] + hid0 * sW2[1] + hid1 * sW2[4] + hid2 * sW2[7] + hid3 * sW2[10];
    float p2 = sB2[2] + hid0 * sW2[2] + hid1 * sW2[5] + hid2 * sW2[8] + hid3 * sW2[11];
    out[(size_t)e * 3 + 0] = p0;
    out[(size_t)e * 3 + 1] = p1;
    out[(size_t)e * 3 + 2] = p2;
}

// ---------------------------------------------------------------------------
extern "C" void kernel_launch(void* const* d_in, const int* in_sizes, int n_in,
                              void* d_out, int out_size, void* d_ws, size_t ws_size,
                              hipStream_t stream) {
    (void)in_sizes; (void)n_in; (void)out_size; (void)ws_size;
    const float* x   = (const float*)d_in[0];
    // d_in[1] = edge_index (redundant symmetric copy of w2b) — unused
    const int*   w2b = (const int*)d_in[2];
    const float* W1  = (const float*)d_in[3];
    const float* b1  = (const float*)d_in[4];
    const float* W2  = (const float*)d_in[5];
    const float* b2  = (const float*)d_in[6];
    const float* W3  = (const float*)d_in[7];
    const float* b3  = (const float*)d_in[8];
    const float* lw1 = (const float*)d_in[9];
    const float* lb1 = (const float*)d_in[10];
    const float* lw2 = (const float*)d_in[11];
    const float* lb2 = (const float*)d_in[12];
    float* out = (float*)d_out;

    char* ws = (char*)d_ws;
    size_t o = 0;
    auto alloc = [&](size_t bytes) -> void* {
        void* p = ws + o;
        o = (o + bytes + 255) & ~(size_t)255;
        return p;
    };
    int*   cnt  = (int*)  alloc((size_t)N_NODES * 4);        // reused as cursor after scan
    int*   off  = (int*)  alloc((size_t)(N_NODES + 1) * 4);
    float* dinv = (float*)alloc((size_t)N_NODES * 4);
    int*   adj  = (int*)  alloc((size_t)(2L * N_GAMES) * 4); // 12.8 MB
    float* hbuf = (float*)alloc((size_t)N_NODES * 32 * 4);   // 12.8 MB
    // xws aliases d_out (19.2 MB >= 12.8 MB needed); its last read (gather L3)
    // precedes the only write to d_out (edge_mlp).
    float* xws = out;

    const int* wa = w2b;            // w2b[0][:]
    const int* wb = w2b + N_GAMES;  // w2b[1][:]

    const int BLK = 256;
    auto grid = [](long n, int blk) { return dim3((unsigned)((n + blk - 1) / blk)); };

    // ---- CSR build ----
    hipMemsetAsync(cnt, 0, (size_t)N_NODES * 4, stream);
    count_deg_kernel<<<grid(2L * N_GAMES, BLK), BLK, 0, stream>>>(w2b, cnt, 2 * N_GAMES);
    dinv_kernel<<<grid(N_NODES, BLK), BLK, 0, stream>>>(cnt, dinv, N_NODES);
    scan_offsets_kernel<<<1, SCAN_T, 0, stream>>>(cnt, off);
    copy_int_kernel<<<grid(N_NODES, BLK), BLK, 0, stream>>>(off, cnt, N_NODES);  // cnt := cursor
    fill_csr_kernel<<<grid(N_GAMES, BLK), BLK, 0, stream>>>(wa, wb, cnt, adj, N_GAMES);

    // ---- layer 1: 7 -> 8 ----
    node_linear_scaled_kernel<7, 8><<<grid(N_NODES, BLK), BLK, 0, stream>>>(x, W1, dinv, xws, N_NODES);
    gather_combine_kernel<8><<<grid((long)N_NODES * 2, BLK), BLK, 0, stream>>>(off, adj, dinv, xws, b1, hbuf, N_NODES);

    // ---- layer 2: 8 -> 16 ----
    node_linear_scaled_kernel<8, 16><<<grid(N_NODES, BLK), BLK, 0, stream>>>(hbuf, W2, dinv, xws, N_NODES);
    gather_combine_kernel<16><<<grid((long)N_NODES * 4, BLK), BLK, 0, stream>>>(off, adj, dinv, xws, b2, hbuf, N_NODES);

    // ---- layer 3: 16 -> 32 ----
    node_linear_scaled_kernel<16, 32><<<grid(N_NODES, BLK), BLK, 0, stream>>>(hbuf, W3, dinv, xws, N_NODES);
    gather_combine_kernel<32><<<grid((long)N_NODES * 8, BLK), BLK, 0, stream>>>(off, adj, dinv, xws, b3, hbuf, N_NODES);

    // ---- edge MLP ----
    edge_mlp_kernel<<<grid(N_GAMES, BLK), BLK, 0, stream>>>(wa, wb, hbuf, lw1, lb1, lw2, lb2, out, N_GAMES);
}

// Round 4
// 464.556 us; speedup vs baseline: 20.3718x; 2.0281x over previous
//
#include <hip/hip_runtime.h>

static constexpr int N_NODES = 100000;
static constexpr int N_GAMES = 1600000;
static constexpr int SHIFT   = 7;
static constexpr int BSIZE   = 1 << SHIFT;                      // 128 nodes / coarse bucket
static constexpr int NB1     = (N_NODES + BSIZE - 1) / BSIZE;   // 782
static constexpr int TILE_E  = 4096;                            // edges per coarse-scatter tile

// ---------------------------------------------------------------------------
// Pass A: coarse histogram of dst>>SHIFT (both directions per game)
__global__ void coarse_hist_kernel(const int* __restrict__ wa, const int* __restrict__ wb,
                                   int* __restrict__ gcnt, int n) {
    __shared__ int lh[NB1];
    for (int t = threadIdx.x; t < NB1; t += blockDim.x) lh[t] = 0;
    __syncthreads();
    for (int e = blockIdx.x * blockDim.x + threadIdx.x; e < n; e += gridDim.x * blockDim.x) {
        int a = wa[e], b = wb[e];
        atomicAdd(&lh[b >> SHIFT], 1);   // entry (dst=b, src=a)
        atomicAdd(&lh[a >> SHIFT], 1);   // entry (dst=a, src=b)
    }
    __syncthreads();
    for (int t = threadIdx.x; t < NB1; t += blockDim.x) {
        int c = lh[t];
        if (c) atomicAdd(&gcnt[t], c);
    }
}

// ---------------------------------------------------------------------------
// Pass B: exclusive scan of 782 coarse counts (single block); also writes
// the working cursor copy and off[N_NODES].
__global__ __launch_bounds__(1024) void coarse_scan_kernel(const int* __restrict__ gcnt,
                                                           int* __restrict__ goff,
                                                           int* __restrict__ gcur,
                                                           int* __restrict__ off) {
    __shared__ int buf[1024];
    int t = threadIdx.x;
    int v = (t < NB1) ? gcnt[t] : 0;
    buf[t] = v;
    __syncthreads();
    for (int d = 1; d < 1024; d <<= 1) {
        int add = (t >= d) ? buf[t - d] : 0;
        __syncthreads();
        buf[t] += add;
        __syncthreads();
    }
    if (t < NB1) {
        int excl = buf[t] - v;
        goff[t] = excl;
        gcur[t] = excl;
    }
    if (t == 0) {
        goff[NB1] = 2 * N_GAMES;
        off[N_NODES] = 2 * N_GAMES;
    }
}

// ---------------------------------------------------------------------------
// Pass C: scatter packed (src<<SHIFT | dst&(BSIZE-1)) into coarse buckets.
// Per-tile LDS histogram -> one global atomic per (block,bucket) -> run writes.
__global__ void coarse_scatter_kernel(const int* __restrict__ wa, const int* __restrict__ wb,
                                      int* __restrict__ gcur, unsigned* __restrict__ packed,
                                      int n) {
    __shared__ int lh[NB1];
    __shared__ int lbase[NB1];
    for (int t = threadIdx.x; t < NB1; t += blockDim.x) lh[t] = 0;
    __syncthreads();
    int e0 = blockIdx.x * TILE_E;
    int e1 = e0 + TILE_E; if (e1 > n) e1 = n;
    for (int e = e0 + threadIdx.x; e < e1; e += blockDim.x) {
        int a = wa[e], b = wb[e];
        atomicAdd(&lh[b >> SHIFT], 1);
        atomicAdd(&lh[a >> SHIFT], 1);
    }
    __syncthreads();
    for (int t = threadIdx.x; t < NB1; t += blockDim.x) {
        int c = lh[t];
        if (c) lbase[t] = atomicAdd(&gcur[t], c);
        lh[t] = 0;
    }
    __syncthreads();
    for (int e = e0 + threadIdx.x; e < e1; e += blockDim.x) {
        int a = wa[e], b = wb[e];
        int bk1 = b >> SHIFT;
        int r1 = atomicAdd(&lh[bk1], 1);
        packed[lbase[bk1] + r1] = ((unsigned)a << SHIFT) | (unsigned)(b & (BSIZE - 1));
        int bk2 = a >> SHIFT;
        int r2 = atomicAdd(&lh[bk2], 1);
        packed[lbase[bk2] + r2] = ((unsigned)b << SHIFT) | (unsigned)(a & (BSIZE - 1));
    }
}

// ---------------------------------------------------------------------------
// Pass D: one block per coarse bucket. Fine counting-sort by low SHIFT bits:
// writes per-node off[] and the final adj[] (src ids), dense in an L2 window.
__global__ void fine_sort_kernel(const int* __restrict__ goff, const unsigned* __restrict__ packed,
                                 int* __restrict__ off, int* __restrict__ adj) {
    __shared__ int lh[BSIZE];
    __shared__ int buf[BSIZE];
    __shared__ int foff[BSIZE];
    int bkt = blockIdx.x;
    int base = goff[bkt], end = goff[bkt + 1];
    int size = end - base;
    int t = threadIdx.x;
    if (t < BSIZE) lh[t] = 0;
    __syncthreads();
    for (int k = t; k < size; k += blockDim.x)
        atomicAdd(&lh[packed[base + k] & (BSIZE - 1)], 1);
    __syncthreads();
    if (t < BSIZE) buf[t] = lh[t];
    __syncthreads();
    for (int d = 1; d < BSIZE; d <<= 1) {
        int add = (t < BSIZE && t >= d) ? buf[t - d] : 0;
        __syncthreads();
        if (t < BSIZE) buf[t] += add;
        __syncthreads();
    }
    if (t < BSIZE) {
        int excl = buf[t] - lh[t];
        foff[t] = excl;
        int node = bkt * BSIZE + t;
        if (node < N_NODES) off[node] = base + excl;
        lh[t] = 0;
    }
    __syncthreads();
    for (int k = t; k < size; k += blockDim.x) {
        unsigned u = packed[base + k];
        int d = (int)(u & (BSIZE - 1));
        int r = atomicAdd(&lh[d], 1);
        adj[base + foff[d] + r] = (int)(u >> SHIFT);
    }
}

// ---------------------------------------------------------------------------
__global__ void dinv_from_off_kernel(const int* __restrict__ off, float* __restrict__ dinv, int n) {
    int i = blockIdx.x * blockDim.x + threadIdx.x;
    if (i < n) dinv[i] = rsqrtf((float)(off[i + 1] - off[i]) + 1.0f);
}

// ---------------------------------------------------------------------------
// xws = (h @ W) * dinv[i]
template<int FIN, int FOUT>
__global__ void node_linear_scaled_kernel(const float* __restrict__ h, const float* __restrict__ W,
                                          const float* __restrict__ dinv,
                                          float* __restrict__ xws, int n) {
    __shared__ float sW[FIN * FOUT];
    for (int k = threadIdx.x; k < FIN * FOUT; k += blockDim.x) sW[k] = W[k];
    __syncthreads();
    int i = blockIdx.x * blockDim.x + threadIdx.x;
    if (i >= n) return;
    float hin[FIN];
#pragma unroll
    for (int k = 0; k < FIN; ++k) hin[k] = h[(size_t)i * FIN + k];
    float d = dinv[i];
#pragma unroll
    for (int j = 0; j < FOUT; ++j) {
        float acc = 0.0f;
#pragma unroll
        for (int k = 0; k < FIN; ++k) acc += hin[k] * sW[k * FOUT + j];
        xws[(size_t)i * FOUT + j] = acc * d;
    }
}

// ---------------------------------------------------------------------------
// out[i] = relu(dinv[i] * (sum_nbr xws[nbr] + xws[i]) + bias)
// TPN threads per node; each owns FOUT/TPN consecutive features; adj read once
// per thread (TPN<=2 -> at most 2x, vs 8x in the old feature-split version).
template<int FOUT, int TPN>
__global__ void gather_combine_kernel(const int* __restrict__ off, const int* __restrict__ adj,
                                      const float* __restrict__ dinv, const float* __restrict__ xws,
                                      const float* __restrict__ bias, float* __restrict__ out, int n) {
    constexpr int QT = FOUT / 4 / TPN;  // float4s per thread
    int tid = blockIdx.x * blockDim.x + threadIdx.x;
    int i = tid / TPN;
    int h = tid - i * TPN;
    if (i >= n) return;
    const float4* x4 = reinterpret_cast<const float4*>(xws);
    float4 acc[QT];
    size_t self = (size_t)i * (FOUT / 4) + h * QT;
#pragma unroll
    for (int j = 0; j < QT; ++j) acc[j] = x4[self + j];  // self-loop term
    int lo = off[i], hi = off[i + 1];
    for (int k = lo; k < hi; ++k) {
        int nb = adj[k];
        size_t rb = (size_t)nb * (FOUT / 4) + h * QT;
#pragma unroll
        for (int j = 0; j < QT; ++j) {
            float4 v = x4[rb + j];
            acc[j].x += v.x; acc[j].y += v.y; acc[j].z += v.z; acc[j].w += v.w;
        }
    }
    float d = dinv[i];
#pragma unroll
    for (int j = 0; j < QT; ++j) {
        int fb = h * QT * 4 + j * 4;
        float4 r;
        r.x = fmaxf(acc[j].x * d + bias[fb + 0], 0.0f);
        r.y = fmaxf(acc[j].y * d + bias[fb + 1], 0.0f);
        r.z = fmaxf(acc[j].z * d + bias[fb + 2], 0.0f);
        r.w = fmaxf(acc[j].w * d + bias[fb + 3], 0.0f);
        reinterpret_cast<float4*>(out)[self + j] = r;
    }
}

// ---------------------------------------------------------------------------
// per-game MLP: concat(h[a], h[b]) @ lw1 + lb1 -> @ lw2 + lb2  (no relu)
__global__ void edge_mlp_kernel(const int* __restrict__ wa, const int* __restrict__ wb,
                                const float* __restrict__ h,
                                const float* __restrict__ lw1, const float* __restrict__ lb1,
                                const float* __restrict__ lw2, const float* __restrict__ lb2,
                                float* __restrict__ out, int ngames) {
    __shared__ float sW1[256];
    __shared__ float sB1[4];
    __shared__ float sW2[12];
    __shared__ float sB2[3];
    for (int k = threadIdx.x; k < 256; k += blockDim.x) sW1[k] = lw1[k];
    if (threadIdx.x < 4) sB1[threadIdx.x] = lb1[threadIdx.x];
    if (threadIdx.x < 12) sW2[threadIdx.x] = lw2[threadIdx.x];
    if (threadIdx.x < 3) sB2[threadIdx.x] = lb2[threadIdx.x];
    __syncthreads();
    int e = blockIdx.x * blockDim.x + threadIdx.x;
    if (e >= ngames) return;
    int a = wa[e], b = wb[e];
    float hid0 = sB1[0], hid1 = sB1[1], hid2 = sB1[2], hid3 = sB1[3];
    const float4* h4 = reinterpret_cast<const float4*>(h);
#pragma unroll
    for (int k4 = 0; k4 < 8; ++k4) {
        float4 v = h4[(size_t)a * 8 + k4];
        const float* w = sW1 + (k4 * 4) * 4;
        hid0 += v.x * w[0] + v.y * w[4] + v.z * w[8]  + v.w * w[12];
        hid1 += v.x * w[1] + v.y * w[5] + v.z * w[9]  + v.w * w[13];
        hid2 += v.x * w[2] + v.y * w[6] + v.z * w[10] + v.w * w[14];
        hid3 += v.x * w[3] + v.y * w[7] + v.z * w[11] + v.w * w[15];
    }
#pragma unroll
    for (int k4 = 0; k4 < 8; ++k4) {
        float4 v = h4[(size_t)b * 8 + k4];
        const float* w = sW1 + (32 + k4 * 4) * 4;
        hid0 += v.x * w[0] + v.y * w[4] + v.z * w[8]  + v.w * w[12];
        hid1 += v.x * w[1] + v.y * w[5] + v.z * w[9]  + v.w * w[13];
        hid2 += v.x * w[2] + v.y * w[6] + v.z * w[10] + v.w * w[14];
        hid3 += v.x * w[3] + v.y * w[7] + v.z * w[11] + v.w * w[15];
    }
    float p0 = sB2[0] + hid0 * sW2[0] + hid1 * sW2[3] + hid2 * sW2[6] + hid3 * sW2[9];
    float p1 = sB2[1] + hid0 * sW2[1] + hid1 * sW2[4] + hid2 * sW2[7] + hid3 * sW2[10];
    float p2 = sB2[2] + hid0 * sW2[2] + hid1 * sW2[5] + hid2 * sW2[8] + hid3 * sW2[11];
    out[(size_t)e * 3 + 0] = p0;
    out[(size_t)e * 3 + 1] = p1;
    out[(size_t)e * 3 + 2] = p2;
}

// ---------------------------------------------------------------------------
extern "C" void kernel_launch(void* const* d_in, const int* in_sizes, int n_in,
                              void* d_out, int out_size, void* d_ws, size_t ws_size,
                              hipStream_t stream) {
    (void)in_sizes; (void)n_in; (void)out_size; (void)ws_size;
    const float* x   = (const float*)d_in[0];
    const int*   w2b = (const int*)d_in[2];
    const float* W1  = (const float*)d_in[3];
    const float* b1  = (const float*)d_in[4];
    const float* W2  = (const float*)d_in[5];
    const float* b2  = (const float*)d_in[6];
    const float* W3  = (const float*)d_in[7];
    const float* b3  = (const float*)d_in[8];
    const float* lw1 = (const float*)d_in[9];
    const float* lb1 = (const float*)d_in[10];
    const float* lw2 = (const float*)d_in[11];
    const float* lb2 = (const float*)d_in[12];
    float* out = (float*)d_out;

    char* ws = (char*)d_ws;
    size_t o = 0;
    auto alloc = [&](size_t bytes) -> void* {
        void* p = ws + o;
        o = (o + bytes + 255) & ~(size_t)255;
        return p;
    };
    int*      gcnt   = (int*)     alloc((size_t)(NB1 + 1) * 4);
    int*      goff   = (int*)     alloc((size_t)(NB1 + 1) * 4);
    int*      gcur   = (int*)     alloc((size_t)NB1 * 4);
    int*      off    = (int*)     alloc((size_t)(N_NODES + 1) * 4);
    float*    dinv   = (float*)   alloc((size_t)N_NODES * 4);
    unsigned* packed = (unsigned*)alloc((size_t)(2L * N_GAMES) * 4);  // 12.8 MB
    int*      adj    = (int*)     alloc((size_t)(2L * N_GAMES) * 4);  // 12.8 MB
    // hbuf aliases packed: packed's last read (fine_sort) precedes hbuf's first
    // write (layer-1 gather). xws aliases d_out (19.2 MB >= 12.8 MB needed);
    // its last read precedes the only write to d_out (edge_mlp).
    float* hbuf = (float*)packed;
    float* xws  = out;

    const int* wa = w2b;            // w2b[0][:]
    const int* wb = w2b + N_GAMES;  // w2b[1][:]

    const int BLK = 256;
    auto grid = [](long n, int blk) { return dim3((unsigned)((n + blk - 1) / blk)); };

    // ---- CSR build via two-level bucket sort (no global float atomics, no cursors) ----
    hipMemsetAsync(gcnt, 0, (size_t)(NB1 + 1) * 4, stream);
    coarse_hist_kernel<<<512, BLK, 0, stream>>>(wa, wb, gcnt, N_GAMES);
    coarse_scan_kernel<<<1, 1024, 0, stream>>>(gcnt, goff, gcur, off);
    coarse_scatter_kernel<<<grid(N_GAMES, TILE_E), BLK, 0, stream>>>(wa, wb, gcur, packed, N_GAMES);
    fine_sort_kernel<<<NB1, BLK, 0, stream>>>(goff, packed, off, adj);
    dinv_from_off_kernel<<<grid(N_NODES, BLK), BLK, 0, stream>>>(off, dinv, N_NODES);

    // ---- layer 1: 7 -> 8 ----
    node_linear_scaled_kernel<7, 8><<<grid(N_NODES, BLK), BLK, 0, stream>>>(x, W1, dinv, xws, N_NODES);
    gather_combine_kernel<8, 1><<<grid(N_NODES, BLK), BLK, 0, stream>>>(off, adj, dinv, xws, b1, hbuf, N_NODES);

    // ---- layer 2: 8 -> 16 ----
    node_linear_scaled_kernel<8, 16><<<grid(N_NODES, BLK), BLK, 0, stream>>>(hbuf, W2, dinv, xws, N_NODES);
    gather_combine_kernel<16, 1><<<grid(N_NODES, BLK), BLK, 0, stream>>>(off, adj, dinv, xws, b2, hbuf, N_NODES);

    // ---- layer 3: 16 -> 32 ----
    node_linear_scaled_kernel<16, 32><<<grid(N_NODES, BLK), BLK, 0, stream>>>(hbuf, W3, dinv, xws, N_NODES);
    gather_combine_kernel<32, 2><<<grid(2L * N_NODES, BLK), BLK, 0, stream>>>(off, adj, dinv, xws, b3, hbuf, N_NODES);

    // ---- edge MLP ----
    edge_mlp_kernel<<<grid(N_GAMES, BLK), BLK, 0, stream>>>(wa, wb, hbuf, lw1, lb1, lw2, lb2, out, N_GAMES);
}

// Round 9
// 428.311 us; speedup vs baseline: 22.0958x; 1.0846x over previous
//
#include <hip/hip_runtime.h>

static constexpr int N_NODES = 100000;
static constexpr int N_GAMES = 1600000;
static constexpr int SHIFT   = 7;
static constexpr int BSIZE   = 1 << SHIFT;                      // 128 nodes / coarse bucket
static constexpr int NB1     = (N_NODES + BSIZE - 1) / BSIZE;   // 782
static constexpr int CAP     = 4608;                            // padded bucket cap (mean 4096 + 8 sigma)
static constexpr int TILE_E  = 4096;                            // games per coarse-scatter tile

// ---------------------------------------------------------------------------
// Pass A: scatter packed (src<<SHIFT | dst&127) into PADDED coarse buckets.
// Per-tile LDS histogram -> one global atomic per (block,bucket) -> run writes.
// Padding removes the need for a global histogram + scan pass entirely.
__global__ void coarse_scatter_kernel(const int* __restrict__ wa, const int* __restrict__ wb,
                                      int* __restrict__ gcur, unsigned* __restrict__ packed,
                                      int n) {
    __shared__ int lh[NB1];
    __shared__ int lbase[NB1];
    for (int t = threadIdx.x; t < NB1; t += blockDim.x) lh[t] = 0;
    __syncthreads();
    int e0 = blockIdx.x * TILE_E;
    int e1 = e0 + TILE_E; if (e1 > n) e1 = n;
    for (int e = e0 + threadIdx.x; e < e1; e += blockDim.x) {
        int a = wa[e], b = wb[e];
        atomicAdd(&lh[b >> SHIFT], 1);   // entry (dst=b, src=a)
        atomicAdd(&lh[a >> SHIFT], 1);   // entry (dst=a, src=b)
    }
    __syncthreads();
    for (int t = threadIdx.x; t < NB1; t += blockDim.x) {
        int c = lh[t];
        if (c) lbase[t] = atomicAdd(&gcur[t], c);
        lh[t] = 0;
    }
    __syncthreads();
    for (int e = e0 + threadIdx.x; e < e1; e += blockDim.x) {
        int a = wa[e], b = wb[e];
        int bk1 = b >> SHIFT;
        int r1 = lbase[bk1] + atomicAdd(&lh[bk1], 1);
        if (r1 < CAP) packed[(size_t)bk1 * CAP + r1] = ((unsigned)a << SHIFT) | (unsigned)(b & (BSIZE - 1));
        int bk2 = a >> SHIFT;
        int r2 = lbase[bk2] + atomicAdd(&lh[bk2], 1);
        if (r2 < CAP) packed[(size_t)bk2 * CAP + r2] = ((unsigned)b << SHIFT) | (unsigned)(a & (BSIZE - 1));
    }
}

// ---------------------------------------------------------------------------
// Pass B: one block per coarse bucket. Fine counting-sort by low SHIFT bits:
// writes per-node off[]/deg[] and the final adj[] (src ids), padded layout.
__global__ void fine_sort_kernel(const int* __restrict__ gcur, const unsigned* __restrict__ packed,
                                 int* __restrict__ off, int* __restrict__ deg, int* __restrict__ adj) {
    __shared__ int lh[BSIZE];
    __shared__ int buf[BSIZE];
    __shared__ int foff[BSIZE];
    int bkt = blockIdx.x;
    int size = gcur[bkt]; if (size > CAP) size = CAP;
    int base = bkt * CAP;
    int t = threadIdx.x;
    if (t < BSIZE) lh[t] = 0;
    __syncthreads();
    for (int k = t; k < size; k += blockDim.x)
        atomicAdd(&lh[packed[base + k] & (BSIZE - 1)], 1);
    __syncthreads();
    if (t < BSIZE) buf[t] = lh[t];
    __syncthreads();
    for (int d = 1; d < BSIZE; d <<= 1) {
        int add = (t < BSIZE && t >= d) ? buf[t - d] : 0;
        __syncthreads();
        if (t < BSIZE) buf[t] += add;
        __syncthreads();
    }
    if (t < BSIZE) {
        int excl = buf[t] - lh[t];
        foff[t] = excl;
        int node = bkt * BSIZE + t;
        if (node < N_NODES) {
            off[node] = base + excl;
            deg[node] = lh[t];
        }
        lh[t] = 0;
    }
    __syncthreads();
    for (int k = t; k < size; k += blockDim.x) {
        unsigned u = packed[base + k];
        int d = (int)(u & (BSIZE - 1));
        int r = atomicAdd(&lh[d], 1);
        adj[base + foff[d] + r] = (int)(u >> SHIFT);
    }
}

// ---------------------------------------------------------------------------
__global__ void dinv_from_deg_kernel(const int* __restrict__ deg, float* __restrict__ dinv, int n) {
    int i = blockIdx.x * blockDim.x + threadIdx.x;
    if (i < n) dinv[i] = rsqrtf((float)deg[i] + 1.0f);
}

// ---------------------------------------------------------------------------
// xws = (h @ W) * dinv[i]
template<int FIN, int FOUT>
__global__ void node_linear_scaled_kernel(const float* __restrict__ h, const float* __restrict__ W,
                                          const float* __restrict__ dinv,
                                          float* __restrict__ xws, int n) {
    __shared__ float sW[FIN * FOUT];
    for (int k = threadIdx.x; k < FIN * FOUT; k += blockDim.x) sW[k] = W[k];
    __syncthreads();
    int i = blockIdx.x * blockDim.x + threadIdx.x;
    if (i >= n) return;
    float hin[FIN];
#pragma unroll
    for (int k = 0; k < FIN; ++k) hin[k] = h[(size_t)i * FIN + k];
    float d = dinv[i];
#pragma unroll
    for (int j = 0; j < FOUT; ++j) {
        float acc = 0.0f;
#pragma unroll
        for (int k = 0; k < FIN; ++k) acc += hin[k] * sW[k * FOUT + j];
        xws[(size_t)i * FOUT + j] = acc * d;
    }
}

// ---------------------------------------------------------------------------
// out[i] = relu(dinv[i] * (sum_nbr xws[nbr] + xws[i]) + bias)   (layers 1,2)
template<int FOUT>
__global__ void gather_combine_kernel(const int* __restrict__ off, const int* __restrict__ deg,
                                      const int* __restrict__ adj,
                                      const float* __restrict__ dinv, const float* __restrict__ xws,
                                      const float* __restrict__ bias, float* __restrict__ out, int n) {
    constexpr int Q = FOUT / 4;
    int i = blockIdx.x * blockDim.x + threadIdx.x;
    if (i >= n) return;
    const float4* x4 = reinterpret_cast<const float4*>(xws);
    float4 acc[Q];
    size_t self = (size_t)i * Q;
#pragma unroll
    for (int j = 0; j < Q; ++j) acc[j] = x4[self + j];  // self-loop term
    int lo = off[i], hi = lo + deg[i];
    for (int k = lo; k < hi; ++k) {
        int nb = adj[k];
        size_t rb = (size_t)nb * Q;
#pragma unroll
        for (int j = 0; j < Q; ++j) {
            float4 v = x4[rb + j];
            acc[j].x += v.x; acc[j].y += v.y; acc[j].z += v.z; acc[j].w += v.w;
        }
    }
    float d = dinv[i];
#pragma unroll
    for (int j = 0; j < Q; ++j) {
        float4 r;
        r.x = fmaxf(acc[j].x * d + bias[j * 4 + 0], 0.0f);
        r.y = fmaxf(acc[j].y * d + bias[j * 4 + 1], 0.0f);
        r.z = fmaxf(acc[j].z * d + bias[j * 4 + 2], 0.0f);
        r.w = fmaxf(acc[j].w * d + bias[j * 4 + 3], 0.0f);
        reinterpret_cast<float4*>(out)[self + j] = r;
    }
}

// ---------------------------------------------------------------------------
// Layer 3 gather fused with the split edge-MLP projection:
//   h3 = relu(dinv*(agg)+b3) computed in registers, then
//   pa[i] = h3 @ lw1[0:32][:],  pb[i] = h3 @ lw1[32:64][:]   (4 floats each).
// h3 is never materialized; edge_mlp later gathers 16 B per endpoint.
__global__ void gather_project32_kernel(const int* __restrict__ off, const int* __restrict__ deg,
                                        const int* __restrict__ adj,
                                        const float* __restrict__ dinv, const float* __restrict__ xws,
                                        const float* __restrict__ b3, const float* __restrict__ lw1,
                                        float4* __restrict__ pa4, float4* __restrict__ pb4, int n) {
    __shared__ float sW[256];   // lw1: [64][4] row-major
    __shared__ float sB[32];
    for (int k = threadIdx.x; k < 256; k += blockDim.x) sW[k] = lw1[k];
    if (threadIdx.x < 32) sB[threadIdx.x] = b3[threadIdx.x];
    __syncthreads();
    int i = blockIdx.x * blockDim.x + threadIdx.x;
    if (i >= n) return;
    const float4* x4 = reinterpret_cast<const float4*>(xws);
    float4 acc[8];
    size_t self = (size_t)i * 8;
#pragma unroll
    for (int j = 0; j < 8; ++j) acc[j] = x4[self + j];  // self-loop term
    int lo = off[i], hi = lo + deg[i];
    for (int k = lo; k < hi; ++k) {
        int nb = adj[k];
        size_t rb = (size_t)nb * 8;
#pragma unroll
        for (int j = 0; j < 8; ++j) {
            float4 v = x4[rb + j];
            acc[j].x += v.x; acc[j].y += v.y; acc[j].z += v.z; acc[j].w += v.w;
        }
    }
    float d = dinv[i];
    float h3[32];
#pragma unroll
    for (int j = 0; j < 8; ++j) {
        h3[j * 4 + 0] = fmaxf(acc[j].x * d + sB[j * 4 + 0], 0.0f);
        h3[j * 4 + 1] = fmaxf(acc[j].y * d + sB[j * 4 + 1], 0.0f);
        h3[j * 4 + 2] = fmaxf(acc[j].z * d + sB[j * 4 + 2], 0.0f);
        h3[j * 4 + 3] = fmaxf(acc[j].w * d + sB[j * 4 + 3], 0.0f);
    }
    float pa[4] = {0.f, 0.f, 0.f, 0.f};
    float pb[4] = {0.f, 0.f, 0.f, 0.f};
#pragma unroll
    for (int k = 0; k < 32; ++k) {
#pragma unroll
        for (int j = 0; j < 4; ++j) {
            pa[j] += h3[k] * sW[k * 4 + j];
            pb[j] += h3[k] * sW[(32 + k) * 4 + j];
        }
    }
    pa4[i] = make_float4(pa[0], pa[1], pa[2], pa[3]);
    pb4[i] = make_float4(pb[0], pb[1], pb[2], pb[3]);
}

// ---------------------------------------------------------------------------
// per-game MLP on projected features: hidden = pa[a] + pb[b] + lb1; out = hidden@lw2 + lb2
__global__ void edge_mlp_pab_kernel(const int* __restrict__ wa, const int* __restrict__ wb,
                                    const float4* __restrict__ pa4, const float4* __restrict__ pb4,
                                    const float* __restrict__ lb1, const float* __restrict__ lw2,
                                    const float* __restrict__ lb2,
                                    float* __restrict__ out, int ngames) {
    __shared__ float sB1[4];
    __shared__ float sW2[12];
    __shared__ float sB2[3];
    if (threadIdx.x < 4) sB1[threadIdx.x] = lb1[threadIdx.x];
    if (threadIdx.x < 12) sW2[threadIdx.x] = lw2[threadIdx.x];
    if (threadIdx.x < 3) sB2[threadIdx.x] = lb2[threadIdx.x];
    __syncthreads();
    int e = blockIdx.x * blockDim.x + threadIdx.x;
    if (e >= ngames) return;
    int a = wa[e], b = wb[e];
    float4 A = pa4[a];
    float4 B = pb4[b];
    float h0 = A.x + B.x + sB1[0];
    float h1 = A.y + B.y + sB1[1];
    float h2 = A.z + B.z + sB1[2];
    float h3 = A.w + B.w + sB1[3];
    // lw2 is [4][3] row-major
    float p0 = sB2[0] + h0 * sW2[0] + h1 * sW2[3] + h2 * sW2[6] + h3 * sW2[9];
    float p1 = sB2[1] + h0 * sW2[1] + h1 * sW2[4] + h2 * sW2[7] + h3 * sW2[10];
    float p2 = sB2[2] + h0 * sW2[2] + h1 * sW2[5] + h2 * sW2[8] + h3 * sW2[11];
    out[(size_t)e * 3 + 0] = p0;
    out[(size_t)e * 3 + 1] = p1;
    out[(size_t)e * 3 + 2] = p2;
}

// ---------------------------------------------------------------------------
extern "C" void kernel_launch(void* const* d_in, const int* in_sizes, int n_in,
                              void* d_out, int out_size, void* d_ws, size_t ws_size,
                              hipStream_t stream) {
    (void)in_sizes; (void)n_in; (void)out_size; (void)ws_size;
    const float* x   = (const float*)d_in[0];
    const int*   w2b = (const int*)d_in[2];
    const float* W1  = (const float*)d_in[3];
    const float* b1  = (const float*)d_in[4];
    const float* W2  = (const float*)d_in[5];
    const float* b2  = (const float*)d_in[6];
    const float* W3  = (const float*)d_in[7];
    const float* b3  = (const float*)d_in[8];
    const float* lw1 = (const float*)d_in[9];
    const float* lb1 = (const float*)d_in[10];
    const float* lw2 = (const float*)d_in[11];
    const float* lb2 = (const float*)d_in[12];
    float* out = (float*)d_out;

    char* ws = (char*)d_ws;
    size_t o = 0;
    auto alloc = [&](size_t bytes) -> void* {
        void* p = ws + o;
        o = (o + bytes + 255) & ~(size_t)255;
        return p;
    };
    int*      gcur   = (int*)     alloc((size_t)NB1 * 4);
    int*      off    = (int*)     alloc((size_t)N_NODES * 4);
    int*      deg    = (int*)     alloc((size_t)N_NODES * 4);
    float*    dinv   = (float*)   alloc((size_t)N_NODES * 4);
    unsigned* packed = (unsigned*)alloc((size_t)NB1 * CAP * 4);   // 14.4 MB
    int*      adj    = (int*)     alloc((size_t)NB1 * CAP * 4);   // 14.4 MB

    // Aliases into `packed` (dead after fine_sort; these are written only after):
    //   hbuf: [0, 6.4 MB)   pa4: [8 MB, 9.6 MB)   pb4: [10 MB, 11.6 MB)
    constexpr size_t PA_OFF = (size_t)8  << 20;
    constexpr size_t PB_OFF = (size_t)10 << 20;
    float*  hbuf = (float*)packed;
    float4* pa4  = (float4*)((char*)packed + PA_OFF);
    float4* pb4  = (float4*)((char*)packed + PB_OFF);
    // xws aliases d_out (19.2 MB >= 12.8 MB needed); its last read
    // (gather_project32) precedes the only write to d_out (edge_mlp_pab).
    float* xws = out;

    const int* wa = w2b;            // w2b[0][:]
    const int* wb = w2b + N_GAMES;  // w2b[1][:]

    const int BLK = 256;
    auto grid = [](long n, int blk) { return dim3((unsigned)((n + blk - 1) / blk)); };

    // ---- CSR build: padded two-level bucket sort (2 passes over edges) ----
    (void)hipMemsetAsync(gcur, 0, (size_t)NB1 * 4, stream);
    coarse_scatter_kernel<<<grid(N_GAMES, TILE_E), BLK, 0, stream>>>(wa, wb, gcur, packed, N_GAMES);
    fine_sort_kernel<<<NB1, BLK, 0, stream>>>(gcur, packed, off, deg, adj);
    dinv_from_deg_kernel<<<grid(N_NODES, BLK), BLK, 0, stream>>>(deg, dinv, N_NODES);

    // ---- layer 1: 7 -> 8 ----
    node_linear_scaled_kernel<7, 8><<<grid(N_NODES, BLK), BLK, 0, stream>>>(x, W1, dinv, xws, N_NODES);
    gather_combine_kernel<8><<<grid(N_NODES, BLK), BLK, 0, stream>>>(off, deg, adj, dinv, xws, b1, hbuf, N_NODES);

    // ---- layer 2: 8 -> 16 ----
    node_linear_scaled_kernel<8, 16><<<grid(N_NODES, BLK), BLK, 0, stream>>>(hbuf, W2, dinv, xws, N_NODES);
    gather_combine_kernel<16><<<grid(N_NODES, BLK), BLK, 0, stream>>>(off, deg, adj, dinv, xws, b2, hbuf, N_NODES);

    // ---- layer 3: 16 -> 32, fused with edge-MLP node projection ----
    node_linear_scaled_kernel<16, 32><<<grid(N_NODES, BLK), BLK, 0, stream>>>(hbuf, W3, dinv, xws, N_NODES);
    gather_project32_kernel<<<grid(N_NODES, BLK), BLK, 0, stream>>>(off, deg, adj, dinv, xws, b3, lw1, pa4, pb4, N_NODES);

    // ---- edge MLP on projected features ----
    edge_mlp_pab_kernel<<<grid(N_GAMES, BLK), BLK, 0, stream>>>(wa, wb, pa4, pb4, lb1, lw2, lb2, out, N_GAMES);
}

// Round 12
// 373.533 us; speedup vs baseline: 25.3361x; 1.1466x over previous
//
#include <hip/hip_runtime.h>

static constexpr int N_NODES = 100000;
static constexpr int N_GAMES = 1600000;
static constexpr int SHIFT   = 7;
static constexpr int BSIZE   = 1 << SHIFT;                      // 128 nodes / coarse bucket
static constexpr int NB1     = (N_NODES + BSIZE - 1) / BSIZE;   // 782
static constexpr int CAP     = 4608;                            // padded bucket cap (mean 4096 + 8 sigma)
static constexpr int TILE_E  = 4096;                            // games per coarse-scatter tile

// ---------------------------------------------------------------------------
// Pass A: scatter packed (src<<SHIFT | dst&127) into PADDED coarse buckets.
__global__ void coarse_scatter_kernel(const int* __restrict__ wa, const int* __restrict__ wb,
                                      int* __restrict__ gcur, unsigned* __restrict__ packed,
                                      int n) {
    __shared__ int lh[NB1];
    __shared__ int lbase[NB1];
    for (int t = threadIdx.x; t < NB1; t += blockDim.x) lh[t] = 0;
    __syncthreads();
    int e0 = blockIdx.x * TILE_E;
    int e1 = e0 + TILE_E; if (e1 > n) e1 = n;
    for (int e = e0 + threadIdx.x; e < e1; e += blockDim.x) {
        int a = wa[e], b = wb[e];
        atomicAdd(&lh[b >> SHIFT], 1);   // entry (dst=b, src=a)
        atomicAdd(&lh[a >> SHIFT], 1);   // entry (dst=a, src=b)
    }
    __syncthreads();
    for (int t = threadIdx.x; t < NB1; t += blockDim.x) {
        int c = lh[t];
        if (c) lbase[t] = atomicAdd(&gcur[t], c);
        lh[t] = 0;
    }
    __syncthreads();
    for (int e = e0 + threadIdx.x; e < e1; e += blockDim.x) {
        int a = wa[e], b = wb[e];
        int bk1 = b >> SHIFT;
        int r1 = lbase[bk1] + atomicAdd(&lh[bk1], 1);
        if (r1 < CAP) packed[(size_t)bk1 * CAP + r1] = ((unsigned)a << SHIFT) | (unsigned)(b & (BSIZE - 1));
        int bk2 = a >> SHIFT;
        int r2 = lbase[bk2] + atomicAdd(&lh[bk2], 1);
        if (r2 < CAP) packed[(size_t)bk2 * CAP + r2] = ((unsigned)b << SHIFT) | (unsigned)(a & (BSIZE - 1));
    }
}

// ---------------------------------------------------------------------------
// Pass B: one block per coarse bucket. Fine counting-sort by low SHIFT bits.
__global__ void fine_sort_kernel(const int* __restrict__ gcur, const unsigned* __restrict__ packed,
                                 int* __restrict__ off, int* __restrict__ deg, int* __restrict__ adj) {
    __shared__ int lh[BSIZE];
    __shared__ int buf[BSIZE];
    __shared__ int foff[BSIZE];
    int bkt = blockIdx.x;
    int size = gcur[bkt]; if (size > CAP) size = CAP;
    int base = bkt * CAP;
    int t = threadIdx.x;
    if (t < BSIZE) lh[t] = 0;
    __syncthreads();
    for (int k = t; k < size; k += blockDim.x)
        atomicAdd(&lh[packed[base + k] & (BSIZE - 1)], 1);
    __syncthreads();
    if (t < BSIZE) buf[t] = lh[t];
    __syncthreads();
    for (int d = 1; d < BSIZE; d <<= 1) {
        int add = (t < BSIZE && t >= d) ? buf[t - d] : 0;
        __syncthreads();
        if (t < BSIZE) buf[t] += add;
        __syncthreads();
    }
    if (t < BSIZE) {
        int excl = buf[t] - lh[t];
        foff[t] = excl;
        int node = bkt * BSIZE + t;
        if (node < N_NODES) {
            off[node] = base + excl;
            deg[node] = lh[t];
        }
        lh[t] = 0;
    }
    __syncthreads();
    for (int k = t; k < size; k += blockDim.x) {
        unsigned u = packed[base + k];
        int d = (int)(u & (BSIZE - 1));
        int r = atomicAdd(&lh[d], 1);
        adj[base + foff[d] + r] = (int)(u >> SHIFT);
    }
}

// ---------------------------------------------------------------------------
__global__ void dinv_from_deg_kernel(const int* __restrict__ deg, float* __restrict__ dinv, int n) {
    int i = blockIdx.x * blockDim.x + threadIdx.x;
    if (i < n) dinv[i] = rsqrtf((float)deg[i] + 1.0f);
}

// ---------------------------------------------------------------------------
// xws = (h @ W) * dinv[i]
template<int FIN, int FOUT>
__global__ void node_linear_scaled_kernel(const float* __restrict__ h, const float* __restrict__ W,
                                          const float* __restrict__ dinv,
                                          float* __restrict__ xws, int n) {
    __shared__ float sW[FIN * FOUT];
    for (int k = threadIdx.x; k < FIN * FOUT; k += blockDim.x) sW[k] = W[k];
    __syncthreads();
    int i = blockIdx.x * blockDim.x + threadIdx.x;
    if (i >= n) return;
    float hin[FIN];
#pragma unroll
    for (int k = 0; k < FIN; ++k) hin[k] = h[(size_t)i * FIN + k];
    float d = dinv[i];
#pragma unroll
    for (int j = 0; j < FOUT; ++j) {
        float acc = 0.0f;
#pragma unroll
        for (int k = 0; k < FIN; ++k) acc += hin[k] * sW[k * FOUT + j];
        xws[(size_t)i * FOUT + j] = acc * d;
    }
}

// ---------------------------------------------------------------------------
// out[i] = relu(dinv[i] * (sum_nbr xws[nbr] + xws[i]) + bias)   (layers 1,2)
// TPN threads per node, FEATURE-split: thread h owns quads [h*QT, (h+1)*QT).
// adj is re-read TPN x (coalesced, cheap); parallelism is TPN x (the lever:
// R9 showed 1 thread/node = 13% occupancy, latency-bound).
template<int FOUT, int TPN>
__global__ void gather_combine_kernel(const int* __restrict__ off, const int* __restrict__ deg,
                                      const int* __restrict__ adj,
                                      const float* __restrict__ dinv, const float* __restrict__ xws,
                                      const float* __restrict__ bias, float* __restrict__ out, long n) {
    constexpr int Q  = FOUT / 4;
    constexpr int QT = Q / TPN;
    long tid = (long)blockIdx.x * blockDim.x + threadIdx.x;
    if (tid >= n * TPN) return;
    int i = (int)(tid / TPN);
    int h = (int)(tid - (long)i * TPN);
    const float4* x4 = reinterpret_cast<const float4*>(xws);
    float4 acc[QT];
    size_t self = (size_t)i * Q + h * QT;
#pragma unroll
    for (int j = 0; j < QT; ++j) acc[j] = x4[self + j];  // self-loop term
    int lo = off[i], hi = lo + deg[i];
    for (int k = lo; k < hi; ++k) {
        int nb = adj[k];
        size_t rb = (size_t)nb * Q + h * QT;
#pragma unroll
        for (int j = 0; j < QT; ++j) {
            float4 v = x4[rb + j];
            acc[j].x += v.x; acc[j].y += v.y; acc[j].z += v.z; acc[j].w += v.w;
        }
    }
    float d = dinv[i];
#pragma unroll
    for (int j = 0; j < QT; ++j) {
        int fb = (h * QT + j) * 4;
        float4 r;
        r.x = fmaxf(acc[j].x * d + bias[fb + 0], 0.0f);
        r.y = fmaxf(acc[j].y * d + bias[fb + 1], 0.0f);
        r.z = fmaxf(acc[j].z * d + bias[fb + 2], 0.0f);
        r.w = fmaxf(acc[j].w * d + bias[fb + 3], 0.0f);
        reinterpret_cast<float4*>(out)[self + j] = r;
    }
}

// ---------------------------------------------------------------------------
// Layer-3 gather + split edge-MLP projection, TPN=4 feature-split.
// Thread h owns features [8h, 8h+8): gathers 32 B/neighbor, computes its
// partial pa/pb (8 rows of lw1), then 2-step shfl_xor reduces across the
// aligned 4-lane group (one node); lane h==0 writes pa4/pb4.
__global__ void gather_project32_kernel(const int* __restrict__ off, const int* __restrict__ deg,
                                        const int* __restrict__ adj,
                                        const float* __restrict__ dinv, const float* __restrict__ xws,
                                        const float* __restrict__ b3, const float* __restrict__ lw1,
                                        float4* __restrict__ pa4, float4* __restrict__ pb4, long n) {
    __shared__ float sW[256];   // lw1: [64][4] row-major
    __shared__ float sB[32];
    for (int k = threadIdx.x; k < 256; k += blockDim.x) sW[k] = lw1[k];
    if (threadIdx.x < 32) sB[threadIdx.x] = b3[threadIdx.x];
    __syncthreads();
    long tid = (long)blockIdx.x * blockDim.x + threadIdx.x;
    if (tid >= n * 4) return;
    int i = (int)(tid >> 2);
    int h = (int)(tid & 3);
    const float4* x4 = reinterpret_cast<const float4*>(xws);
    float4 acc0, acc1;
    size_t self = (size_t)i * 8 + h * 2;
    acc0 = x4[self + 0];
    acc1 = x4[self + 1];
    int lo = off[i], hi = lo + deg[i];
    for (int k = lo; k < hi; ++k) {
        int nb = adj[k];
        size_t rb = (size_t)nb * 8 + h * 2;
        float4 v0 = x4[rb + 0];
        float4 v1 = x4[rb + 1];
        acc0.x += v0.x; acc0.y += v0.y; acc0.z += v0.z; acc0.w += v0.w;
        acc1.x += v1.x; acc1.y += v1.y; acc1.z += v1.z; acc1.w += v1.w;
    }
    float d = dinv[i];
    int fb = h * 8;
    float h3[8];
    h3[0] = fmaxf(acc0.x * d + sB[fb + 0], 0.0f);
    h3[1] = fmaxf(acc0.y * d + sB[fb + 1], 0.0f);
    h3[2] = fmaxf(acc0.z * d + sB[fb + 2], 0.0f);
    h3[3] = fmaxf(acc0.w * d + sB[fb + 3], 0.0f);
    h3[4] = fmaxf(acc1.x * d + sB[fb + 4], 0.0f);
    h3[5] = fmaxf(acc1.y * d + sB[fb + 5], 0.0f);
    h3[6] = fmaxf(acc1.z * d + sB[fb + 6], 0.0f);
    h3[7] = fmaxf(acc1.w * d + sB[fb + 7], 0.0f);
    float pa[4] = {0.f, 0.f, 0.f, 0.f};
    float pb[4] = {0.f, 0.f, 0.f, 0.f};
#pragma unroll
    for (int k = 0; k < 8; ++k) {
        int row = fb + k;
#pragma unroll
        for (int j = 0; j < 4; ++j) {
            pa[j] += h3[k] * sW[row * 4 + j];
            pb[j] += h3[k] * sW[(32 + row) * 4 + j];
        }
    }
    // reduce across the 4 lanes of this node (lanes differ only in h; groups
    // are aligned since blockDim % 4 == 0)
#pragma unroll
    for (int j = 0; j < 4; ++j) {
        pa[j] += __shfl_xor(pa[j], 1);
        pa[j] += __shfl_xor(pa[j], 2);
        pb[j] += __shfl_xor(pb[j], 1);
        pb[j] += __shfl_xor(pb[j], 2);
    }
    if (h == 0) {
        pa4[i] = make_float4(pa[0], pa[1], pa[2], pa[3]);
        pb4[i] = make_float4(pb[0], pb[1], pb[2], pb[3]);
    }
}

// ---------------------------------------------------------------------------
// per-game MLP on projected features: hidden = pa[a] + pb[b] + lb1; out = hidden@lw2 + lb2
__global__ void edge_mlp_pab_kernel(const int* __restrict__ wa, const int* __restrict__ wb,
                                    const float4* __restrict__ pa4, const float4* __restrict__ pb4,
                                    const float* __restrict__ lb1, const float* __restrict__ lw2,
                                    const float* __restrict__ lb2,
                                    float* __restrict__ out, int ngames) {
    __shared__ float sB1[4];
    __shared__ float sW2[12];
    __shared__ float sB2[3];
    if (threadIdx.x < 4) sB1[threadIdx.x] = lb1[threadIdx.x];
    if (threadIdx.x < 12) sW2[threadIdx.x] = lw2[threadIdx.x];
    if (threadIdx.x < 3) sB2[threadIdx.x] = lb2[threadIdx.x];
    __syncthreads();
    int e = blockIdx.x * blockDim.x + threadIdx.x;
    if (e >= ngames) return;
    int a = wa[e], b = wb[e];
    float4 A = pa4[a];
    float4 B = pb4[b];
    float h0 = A.x + B.x + sB1[0];
    float h1 = A.y + B.y + sB1[1];
    float h2 = A.z + B.z + sB1[2];
    float h3 = A.w + B.w + sB1[3];
    // lw2 is [4][3] row-major
    float p0 = sB2[0] + h0 * sW2[0] + h1 * sW2[3] + h2 * sW2[6] + h3 * sW2[9];
    float p1 = sB2[1] + h0 * sW2[1] + h1 * sW2[4] + h2 * sW2[7] + h3 * sW2[10];
    float p2 = sB2[2] + h0 * sW2[2] + h1 * sW2[5] + h2 * sW2[8] + h3 * sW2[11];
    out[(size_t)e * 3 + 0] = p0;
    out[(size_t)e * 3 + 1] = p1;
    out[(size_t)e * 3 + 2] = p2;
}

// ---------------------------------------------------------------------------
extern "C" void kernel_launch(void* const* d_in, const int* in_sizes, int n_in,
                              void* d_out, int out_size, void* d_ws, size_t ws_size,
                              hipStream_t stream) {
    (void)in_sizes; (void)n_in; (void)out_size; (void)ws_size;
    const float* x   = (const float*)d_in[0];
    const int*   w2b = (const int*)d_in[2];
    const float* W1  = (const float*)d_in[3];
    const float* b1  = (const float*)d_in[4];
    const float* W2  = (const float*)d_in[5];
    const float* b2  = (const float*)d_in[6];
    const float* W3  = (const float*)d_in[7];
    const float* b3  = (const float*)d_in[8];
    const float* lw1 = (const float*)d_in[9];
    const float* lb1 = (const float*)d_in[10];
    const float* lw2 = (const float*)d_in[11];
    const float* lb2 = (const float*)d_in[12];
    float* out = (float*)d_out;

    char* ws = (char*)d_ws;
    size_t o = 0;
    auto alloc = [&](size_t bytes) -> void* {
        void* p = ws + o;
        o = (o + bytes + 255) & ~(size_t)255;
        return p;
    };
    int*      gcur   = (int*)     alloc((size_t)NB1 * 4);
    int*      off    = (int*)     alloc((size_t)N_NODES * 4);
    int*      deg    = (int*)     alloc((size_t)N_NODES * 4);
    float*    dinv   = (float*)   alloc((size_t)N_NODES * 4);
    unsigned* packed = (unsigned*)alloc((size_t)NB1 * CAP * 4);   // 14.4 MB
    int*      adj    = (int*)     alloc((size_t)NB1 * CAP * 4);   // 14.4 MB

    // Aliases into `packed` (dead after fine_sort; these are written only after):
    //   hbuf: [0, 6.4 MB)   pa4: [8 MB, 9.6 MB)   pb4: [10 MB, 11.6 MB)
    constexpr size_t PA_OFF = (size_t)8  << 20;
    constexpr size_t PB_OFF = (size_t)10 << 20;
    float*  hbuf = (float*)packed;
    float4* pa4  = (float4*)((char*)packed + PA_OFF);
    float4* pb4  = (float4*)((char*)packed + PB_OFF);
    // xws aliases d_out (19.2 MB >= 12.8 MB needed); its last read
    // (gather_project32) precedes the only write to d_out (edge_mlp_pab).
    float* xws = out;

    const int* wa = w2b;            // w2b[0][:]
    const int* wb = w2b + N_GAMES;  // w2b[1][:]

    const int BLK = 256;
    auto grid = [](long n, int blk) { return dim3((unsigned)((n + blk - 1) / blk)); };

    // ---- CSR build: padded two-level bucket sort (2 passes over edges) ----
    (void)hipMemsetAsync(gcur, 0, (size_t)NB1 * 4, stream);
    coarse_scatter_kernel<<<grid(N_GAMES, TILE_E), BLK, 0, stream>>>(wa, wb, gcur, packed, N_GAMES);
    fine_sort_kernel<<<NB1, BLK, 0, stream>>>(gcur, packed, off, deg, adj);
    dinv_from_deg_kernel<<<grid(N_NODES, BLK), BLK, 0, stream>>>(deg, dinv, N_NODES);

    // ---- layer 1: 7 -> 8 ----
    node_linear_scaled_kernel<7, 8><<<grid(N_NODES, BLK), BLK, 0, stream>>>(x, W1, dinv, xws, N_NODES);
    gather_combine_kernel<8, 2><<<grid(2L * N_NODES, BLK), BLK, 0, stream>>>(off, deg, adj, dinv, xws, b1, hbuf, N_NODES);

    // ---- layer 2: 8 -> 16 ----
    node_linear_scaled_kernel<8, 16><<<grid(N_NODES, BLK), BLK, 0, stream>>>(hbuf, W2, dinv, xws, N_NODES);
    gather_combine_kernel<16, 4><<<grid(4L * N_NODES, BLK), BLK, 0, stream>>>(off, deg, adj, dinv, xws, b2, hbuf, N_NODES);

    // ---- layer 3: 16 -> 32, fused with edge-MLP node projection (TPN=4) ----
    node_linear_scaled_kernel<16, 32><<<grid(N_NODES, BLK), BLK, 0, stream>>>(hbuf, W3, dinv, xws, N_NODES);
    gather_project32_kernel<<<grid(4L * N_NODES, BLK), BLK, 0, stream>>>(off, deg, adj, dinv, xws, b3, lw1, pa4, pb4, N_NODES);

    // ---- edge MLP on projected features ----
    edge_mlp_pab_kernel<<<grid(N_GAMES, BLK), BLK, 0, stream>>>(wa, wb, pa4, pb4, lb1, lw2, lb2, out, N_GAMES);
}

// Round 13
// 347.530 us; speedup vs baseline: 27.2317x; 1.0748x over previous
//
#include <hip/hip_runtime.h>

static constexpr int N_NODES = 100000;
static constexpr int N_GAMES = 1600000;
static constexpr int SHIFT   = 7;
static constexpr int BSIZE   = 1 << SHIFT;                      // 128 nodes / coarse bucket
static constexpr int NB1     = (N_NODES + BSIZE - 1) / BSIZE;   // 782
static constexpr int CAP     = 4608;                            // padded bucket cap (mean 4096 + 8 sigma)
static constexpr int TILE_E  = 4096;                            // games per coarse-scatter tile

// ---------------------------------------------------------------------------
// Pass A: scatter packed (src<<SHIFT | dst&127) into PADDED coarse buckets.
__global__ void coarse_scatter_kernel(const int* __restrict__ wa, const int* __restrict__ wb,
                                      int* __restrict__ gcur, unsigned* __restrict__ packed,
                                      int n) {
    __shared__ int lh[NB1];
    __shared__ int lbase[NB1];
    for (int t = threadIdx.x; t < NB1; t += blockDim.x) lh[t] = 0;
    __syncthreads();
    int e0 = blockIdx.x * TILE_E;
    int e1 = e0 + TILE_E; if (e1 > n) e1 = n;
    for (int e = e0 + threadIdx.x; e < e1; e += blockDim.x) {
        int a = wa[e], b = wb[e];
        atomicAdd(&lh[b >> SHIFT], 1);
        atomicAdd(&lh[a >> SHIFT], 1);
    }
    __syncthreads();
    for (int t = threadIdx.x; t < NB1; t += blockDim.x) {
        int c = lh[t];
        if (c) lbase[t] = atomicAdd(&gcur[t], c);
        lh[t] = 0;
    }
    __syncthreads();
    for (int e = e0 + threadIdx.x; e < e1; e += blockDim.x) {
        int a = wa[e], b = wb[e];
        int bk1 = b >> SHIFT;
        int r1 = lbase[bk1] + atomicAdd(&lh[bk1], 1);
        if (r1 < CAP) packed[(size_t)bk1 * CAP + r1] = ((unsigned)a << SHIFT) | (unsigned)(b & (BSIZE - 1));
        int bk2 = a >> SHIFT;
        int r2 = lbase[bk2] + atomicAdd(&lh[bk2], 1);
        if (r2 < CAP) packed[(size_t)bk2 * CAP + r2] = ((unsigned)b << SHIFT) | (unsigned)(a & (BSIZE - 1));
    }
}

// ---------------------------------------------------------------------------
// Pass B: one block per coarse bucket. Fine counting-sort by low SHIFT bits.
__global__ void fine_sort_kernel(const int* __restrict__ gcur, const unsigned* __restrict__ packed,
                                 int* __restrict__ off, int* __restrict__ deg, int* __restrict__ adj) {
    __shared__ int lh[BSIZE];
    __shared__ int buf[BSIZE];
    __shared__ int foff[BSIZE];
    int bkt = blockIdx.x;
    int size = gcur[bkt]; if (size > CAP) size = CAP;
    int base = bkt * CAP;
    int t = threadIdx.x;
    if (t < BSIZE) lh[t] = 0;
    __syncthreads();
    for (int k = t; k < size; k += blockDim.x)
        atomicAdd(&lh[packed[base + k] & (BSIZE - 1)], 1);
    __syncthreads();
    if (t < BSIZE) buf[t] = lh[t];
    __syncthreads();
    for (int d = 1; d < BSIZE; d <<= 1) {
        int add = (t < BSIZE && t >= d) ? buf[t - d] : 0;
        __syncthreads();
        if (t < BSIZE) buf[t] += add;
        __syncthreads();
    }
    if (t < BSIZE) {
        int excl = buf[t] - lh[t];
        foff[t] = excl;
        int node = bkt * BSIZE + t;
        if (node < N_NODES) {
            off[node] = base + excl;
            deg[node] = lh[t];
        }
        lh[t] = 0;
    }
    __syncthreads();
    for (int k = t; k < size; k += blockDim.x) {
        unsigned u = packed[base + k];
        int d = (int)(u & (BSIZE - 1));
        int r = atomicAdd(&lh[d], 1);
        adj[base + foff[d] + r] = (int)(u >> SHIFT);
    }
}

// ---------------------------------------------------------------------------
__global__ void dinv_from_deg_kernel(const int* __restrict__ deg, float* __restrict__ dinv, int n) {
    int i = blockIdx.x * blockDim.x + threadIdx.x;
    if (i < n) dinv[i] = rsqrtf((float)deg[i] + 1.0f);
}

// ---------------------------------------------------------------------------
// hs0[i*8+f] = f<7 ? x[i*7+f]*dinv[i] : 0   (pad 7 -> 8 for float2 gathers)
__global__ void scale_pad_x_kernel(const float* __restrict__ x, const float* __restrict__ dinv,
                                   float* __restrict__ hs0, int n) {
    int tid = blockIdx.x * blockDim.x + threadIdx.x;
    if (tid >= n * 8) return;
    int i = tid >> 3, f = tid & 7;
    hs0[tid] = (f < 7) ? x[i * 7 + f] * dinv[i] : 0.0f;
}

// ---------------------------------------------------------------------------
// Pre-aggregation gather + fused linear (layers 1,2). FIN padded to 8.
// TPN=4: lane h owns s[2h..2h+2) (one float2/neighbor = 8 B).
// After aggregation, reassemble full s[8] via shfl_xor across the 4-lane
// group, then dst = relu(dinv*(s@W)+bias)*dinv  (pre-scaled for next layer).
template<int KUSE, int FOUT>
__global__ void gather_linear8_kernel(const int* __restrict__ off, const int* __restrict__ deg,
                                      const int* __restrict__ adj,
                                      const float* __restrict__ dinv, const float* __restrict__ src,
                                      const float* __restrict__ W, const float* __restrict__ bias,
                                      float* __restrict__ dst, int n) {
    __shared__ float sW[KUSE * FOUT];
    __shared__ float sB[FOUT];
    for (int k = threadIdx.x; k < KUSE * FOUT; k += blockDim.x) sW[k] = W[k];
    if (threadIdx.x < FOUT) sB[threadIdx.x] = bias[threadIdx.x];
    __syncthreads();
    int tid = blockIdx.x * blockDim.x + threadIdx.x;
    if (tid >= n * 4) return;
    int i = tid >> 2;
    int h = tid & 3;
    const float2* x2 = reinterpret_cast<const float2*>(src);
    float2 acc = x2[(size_t)i * 4 + h];  // self term
    int lo = off[i], hi = lo + deg[i];
    for (int k = lo; k < hi; ++k) {
        int nb = adj[k];
        float2 v = x2[(size_t)nb * 4 + h];
        acc.x += v.x; acc.y += v.y;
    }
    // reassemble s[8] across the aligned 4-lane group (lane h holds s[2h],s[2h+1])
    float p0 = __shfl_xor(acc.x, 1);
    float p1 = __shfl_xor(acc.y, 1);
    bool o1 = (h & 1);
    float q0 = o1 ? p0 : acc.x;   // s[4*(h>>1)+0]
    float q1 = o1 ? p1 : acc.y;
    float q2 = o1 ? acc.x : p0;   // s[4*(h>>1)+2]
    float q3 = o1 ? acc.y : p1;
    float r0 = __shfl_xor(q0, 2);
    float r1 = __shfl_xor(q1, 2);
    float r2 = __shfl_xor(q2, 2);
    float r3 = __shfl_xor(q3, 2);
    bool o2 = (h & 2);
    float s[8];
    s[0] = o2 ? r0 : q0;  s[1] = o2 ? r1 : q1;
    s[2] = o2 ? r2 : q2;  s[3] = o2 ? r3 : q3;
    s[4] = o2 ? q0 : r0;  s[5] = o2 ? q1 : r1;
    s[6] = o2 ? q2 : r2;  s[7] = o2 ? q3 : r3;
    float d = dinv[i];
    constexpr int FO = FOUT / 4;            // outputs per lane
    int j0 = h * FO;
    float r[FO];
#pragma unroll
    for (int jj = 0; jj < FO; ++jj) {
        float t = 0.0f;
#pragma unroll
        for (int k = 0; k < KUSE; ++k) t += s[k] * sW[k * FOUT + j0 + jj];
        r[jj] = fmaxf(d * t + sB[j0 + jj], 0.0f) * d;   // pre-scale for next layer
    }
    if constexpr (FO == 2) {
        reinterpret_cast<float2*>(dst)[(size_t)i * 4 + h] = make_float2(r[0], r[1]);
    } else {
        float4 w4; w4.x = r[0]; w4.y = r[1]; w4.z = r[2]; w4.w = r[3];
        reinterpret_cast<float4*>(dst)[(size_t)i * 4 + h] = w4;
    }
}

// ---------------------------------------------------------------------------
// Layer-3: gather 16-dim h2s (lane h owns s[4h..4h+4), one float4/neighbor),
// reassemble s[16], apply W3 -> h3 (lane's 8 features), relu, then project
// onto lw1 halves (pa/pb partials), shfl-reduce, lane0 writes.
__global__ void gather_project16_kernel(const int* __restrict__ off, const int* __restrict__ deg,
                                        const int* __restrict__ adj,
                                        const float* __restrict__ dinv, const float* __restrict__ src,
                                        const float* __restrict__ W3, const float* __restrict__ b3,
                                        const float* __restrict__ lw1,
                                        float4* __restrict__ pa4, float4* __restrict__ pb4, int n) {
    __shared__ float sW[512];    // W3: [16][32]
    __shared__ float sLW[256];   // lw1: [64][4]
    __shared__ float sB[32];
    for (int k = threadIdx.x; k < 512; k += blockDim.x) sW[k] = W3[k];
    if (threadIdx.x < 256) sLW[threadIdx.x] = lw1[threadIdx.x];
    if (threadIdx.x < 32) sB[threadIdx.x] = b3[threadIdx.x];
    __syncthreads();
    int tid = blockIdx.x * blockDim.x + threadIdx.x;
    if (tid >= n * 4) return;
    int i = tid >> 2;
    int h = tid & 3;
    const float4* x4 = reinterpret_cast<const float4*>(src);
    float4 acc = x4[(size_t)i * 4 + h];  // self term
    int lo = off[i], hi = lo + deg[i];
    for (int k = lo; k < hi; ++k) {
        int nb = adj[k];
        float4 v = x4[(size_t)nb * 4 + h];
        acc.x += v.x; acc.y += v.y; acc.z += v.z; acc.w += v.w;
    }
    // reassemble s[16]: lane h holds s[4h..4h+4)
    float a0 = acc.x, a1 = acc.y, a2 = acc.z, a3 = acc.w;
    float p0 = __shfl_xor(a0, 1), p1 = __shfl_xor(a1, 1),
          p2 = __shfl_xor(a2, 1), p3 = __shfl_xor(a3, 1);
    bool o1 = (h & 1);
    float q[8];
    q[0] = o1 ? p0 : a0;  q[1] = o1 ? p1 : a1;
    q[2] = o1 ? p2 : a2;  q[3] = o1 ? p3 : a3;
    q[4] = o1 ? a0 : p0;  q[5] = o1 ? a1 : p1;
    q[6] = o1 ? a2 : p2;  q[7] = o1 ? a3 : p3;
    float rr[8];
#pragma unroll
    for (int k = 0; k < 8; ++k) rr[k] = __shfl_xor(q[k], 2);
    bool o2 = (h & 2);
    float s[16];
#pragma unroll
    for (int k = 0; k < 8; ++k) {
        s[k]     = o2 ? rr[k] : q[k];
        s[8 + k] = o2 ? q[k]  : rr[k];
    }
    float d = dinv[i];
    int j0 = h * 8;
    float pa[4] = {0.f, 0.f, 0.f, 0.f};
    float pb[4] = {0.f, 0.f, 0.f, 0.f};
#pragma unroll
    for (int jj = 0; jj < 8; ++jj) {
        int j = j0 + jj;
        float t = 0.0f;
#pragma unroll
        for (int k = 0; k < 16; ++k) t += s[k] * sW[k * 32 + j];
        float h3v = fmaxf(d * t + sB[j], 0.0f);
#pragma unroll
        for (int c = 0; c < 4; ++c) {
            pa[c] += h3v * sLW[j * 4 + c];
            pb[c] += h3v * sLW[(32 + j) * 4 + c];
        }
    }
#pragma unroll
    for (int c = 0; c < 4; ++c) {
        pa[c] += __shfl_xor(pa[c], 1);
        pa[c] += __shfl_xor(pa[c], 2);
        pb[c] += __shfl_xor(pb[c], 1);
        pb[c] += __shfl_xor(pb[c], 2);
    }
    if (h == 0) {
        pa4[i] = make_float4(pa[0], pa[1], pa[2], pa[3]);
        pb4[i] = make_float4(pb[0], pb[1], pb[2], pb[3]);
    }
}

// ---------------------------------------------------------------------------
// per-game MLP on projected features: hidden = pa[a] + pb[b] + lb1; out = hidden@lw2 + lb2
__global__ void edge_mlp_pab_kernel(const int* __restrict__ wa, const int* __restrict__ wb,
                                    const float4* __restrict__ pa4, const float4* __restrict__ pb4,
                                    const float* __restrict__ lb1, const float* __restrict__ lw2,
                                    const float* __restrict__ lb2,
                                    float* __restrict__ out, int ngames) {
    __shared__ float sB1[4];
    __shared__ float sW2[12];
    __shared__ float sB2[3];
    if (threadIdx.x < 4) sB1[threadIdx.x] = lb1[threadIdx.x];
    if (threadIdx.x < 12) sW2[threadIdx.x] = lw2[threadIdx.x];
    if (threadIdx.x < 3) sB2[threadIdx.x] = lb2[threadIdx.x];
    __syncthreads();
    int e = blockIdx.x * blockDim.x + threadIdx.x;
    if (e >= ngames) return;
    int a = wa[e], b = wb[e];
    float4 A = pa4[a];
    float4 B = pb4[b];
    float h0 = A.x + B.x + sB1[0];
    float h1 = A.y + B.y + sB1[1];
    float h2 = A.z + B.z + sB1[2];
    float h3 = A.w + B.w + sB1[3];
    float p0 = sB2[0] + h0 * sW2[0] + h1 * sW2[3] + h2 * sW2[6] + h3 * sW2[9];
    float p1 = sB2[1] + h0 * sW2[1] + h1 * sW2[4] + h2 * sW2[7] + h3 * sW2[10];
    float p2 = sB2[2] + h0 * sW2[2] + h1 * sW2[5] + h2 * sW2[8] + h3 * sW2[11];
    out[(size_t)e * 3 + 0] = p0;
    out[(size_t)e * 3 + 1] = p1;
    out[(size_t)e * 3 + 2] = p2;
}

// ---------------------------------------------------------------------------
extern "C" void kernel_launch(void* const* d_in, const int* in_sizes, int n_in,
                              void* d_out, int out_size, void* d_ws, size_t ws_size,
                              hipStream_t stream) {
    (void)in_sizes; (void)n_in; (void)out_size; (void)ws_size;
    const float* x   = (const float*)d_in[0];
    const int*   w2b = (const int*)d_in[2];
    const float* W1  = (const float*)d_in[3];
    const float* b1  = (const float*)d_in[4];
    const float* W2  = (const float*)d_in[5];
    const float* b2  = (const float*)d_in[6];
    const float* W3  = (const float*)d_in[7];
    const float* b3  = (const float*)d_in[8];
    const float* lw1 = (const float*)d_in[9];
    const float* lb1 = (const float*)d_in[10];
    const float* lw2 = (const float*)d_in[11];
    const float* lb2 = (const float*)d_in[12];
    float* out = (float*)d_out;

    char* ws = (char*)d_ws;
    size_t o = 0;
    auto alloc = [&](size_t bytes) -> void* {
        void* p = ws + o;
        o = (o + bytes + 255) & ~(size_t)255;
        return p;
    };
    int*      gcur   = (int*)     alloc((size_t)NB1 * 4);
    int*      off    = (int*)     alloc((size_t)N_NODES * 4);
    int*      deg    = (int*)     alloc((size_t)N_NODES * 4);
    float*    dinv   = (float*)   alloc((size_t)N_NODES * 4);
    unsigned* packed = (unsigned*)alloc((size_t)NB1 * CAP * 4);   // 14.41 MB
    int*      adj    = (int*)     alloc((size_t)NB1 * CAP * 4);   // 14.41 MB

    // Aliases into `packed` (sort staging dead after fine_sort). Lifetimes:
    //   hs0 [0, 3.2M): written by scale_pad, last read by L1 gather
    //   pa4 [0, 1.6M), pb4 [1.7M, 3.3M): written by L3 (after hs0 dead)
    //   h1s [3.4M, 6.6M): L1 -> L2;   h2s [6.8M, 13.2M): L2 -> L3
    float*  hs0 = (float*)packed;
    float4* pa4 = (float4*)packed;
    float4* pb4 = (float4*)((char*)packed + 0x1A0000);
    float*  h1s = (float*)((char*)packed + 0x340000);
    float*  h2s = (float*)((char*)packed + 0x680000);

    const int* wa = w2b;            // w2b[0][:]
    const int* wb = w2b + N_GAMES;  // w2b[1][:]

    const int BLK = 256;
    auto grid = [](long n, int blk) { return dim3((unsigned)((n + blk - 1) / blk)); };

    // ---- CSR build: padded two-level bucket sort (2 passes over edges) ----
    (void)hipMemsetAsync(gcur, 0, (size_t)NB1 * 4, stream);
    coarse_scatter_kernel<<<grid(N_GAMES, TILE_E), BLK, 0, stream>>>(wa, wb, gcur, packed, N_GAMES);
    fine_sort_kernel<<<NB1, BLK, 0, stream>>>(gcur, packed, off, deg, adj);
    dinv_from_deg_kernel<<<grid(N_NODES, BLK), BLK, 0, stream>>>(deg, dinv, N_NODES);

    // ---- input scale+pad: hs0 = [x*dinv | 0], [N,8] ----
    scale_pad_x_kernel<<<grid(8L * N_NODES, BLK), BLK, 0, stream>>>(x, dinv, hs0, N_NODES);

    // ---- layer 1: aggregate hs0 (8-dim), fused 7->8 linear ----
    gather_linear8_kernel<7, 8><<<grid(4L * N_NODES, BLK), BLK, 0, stream>>>(
        off, deg, adj, dinv, hs0, W1, b1, h1s, N_NODES);

    // ---- layer 2: aggregate h1s (8-dim), fused 8->16 linear ----
    gather_linear8_kernel<8, 16><<<grid(4L * N_NODES, BLK), BLK, 0, stream>>>(
        off, deg, adj, dinv, h1s, W2, b2, h2s, N_NODES);

    // ---- layer 3: aggregate h2s (16-dim), fused 16->32 linear + lw1 projection ----
    gather_project16_kernel<<<grid(4L * N_NODES, BLK), BLK, 0, stream>>>(
        off, deg, adj, dinv, h2s, W3, b3, lw1, pa4, pb4, N_NODES);

    // ---- edge MLP on projected features ----
    edge_mlp_pab_kernel<<<grid(N_GAMES, BLK), BLK, 0, stream>>>(wa, wb, pa4, pb4, lb1, lw2, lb2, out, N_GAMES);
}